// Round 17
// baseline (128.395 us; speedup 1.0000x reference)
//
#include <hip/hip_runtime.h>
#include <math.h>

#define D_DIM 4096
#define NWG 1024  // 4 WGs/CU x 256 CUs, persistent grid-stride (16 rows/WG)

typedef float v2f __attribute__((ext_vector_type(2)));

// ---- packed-f32 butterfly primitives (VOP3P) ----
__device__ __forceinline__ v2f bfly0(v2f a) {
    v2f d;
    asm("v_pk_add_f32 %0, %1, %2 op_sel:[0,1] op_sel_hi:[0,1] neg_hi:[0,1]"
        : "=v"(d) : "v"(a), "v"(a));
    return d;
}
__device__ __forceinline__ v2f pkadd(v2f a, v2f b) {
    v2f d; asm("v_pk_add_f32 %0, %1, %2" : "=v"(d) : "v"(a), "v"(b)); return d;
}
__device__ __forceinline__ v2f pksub(v2f a, v2f b) {
    v2f d; asm("v_pk_add_f32 %0, %1, %2 neg_lo:[0,1] neg_hi:[0,1]" : "=v"(d) : "v"(a), "v"(b)); return d;
}
__device__ __forceinline__ v2f pkmul(v2f a, v2f b) {
    v2f d; asm("v_pk_mul_f32 %0, %1, %2" : "=v"(d) : "v"(a), "v"(b)); return d;
}

// In-register FWHT over 4 bits: 16 values as 8 packed v2f.
__device__ __forceinline__ void radix16(v2f w[8]) {
#pragma unroll
    for (int p = 0; p < 8; ++p) w[p] = bfly0(w[p]);
#pragma unroll
    for (int s = 0; s < 3; ++s) {
        const int d = 1 << s;
#pragma unroll
        for (int p = 0; p < 8; ++p) {
            if (!(p & d)) {
                const v2f a = w[p];
                const v2f b = w[p + d];
                w[p]     = pkadd(a, b);
                w[p + d] = pksub(a, b);
            }
        }
    }
}

// async global->LDS, 16 B per lane; LDS dest = wave-uniform base + lane*16.
__device__ __forceinline__ void gload_lds16(const float* g, float* lp) {
    __builtin_amdgcn_global_load_lds(
        (const __attribute__((address_space(1))) void*)g,
        (__attribute__((address_space(3))) void*)lp, 16, 0, 0);
}

// Phase barrier: drain DS ops only (NOT vmcnt -> glds prefetch stays in
// flight across barriers; __syncthreads would emit vmcnt(0) and kill it).
__device__ __forceinline__ void phase_barrier() {
    asm volatile("s_waitcnt lgkmcnt(0)" ::: "memory");
    __builtin_amdgcn_s_barrier();
    __builtin_amdgcn_sched_barrier(0);
}

// Rank-complete transpose-buffer swizzle (verified R11):
//   b4 ^= e8 ^ e5 ;  b3 ^= e7 ;  b2 ^= e9 ^ e6
// Phases A/E (stride-256) and B/D (stride-16): 2-way banks (free);
// phase C b128: at the bank floor. Bijective involution; bits 1:0 untouched.
__device__ __forceinline__ int swzW(int e) {
    const int x4 = ((e >> 8) ^ (e >> 5)) & 1;
    const int x3 = (e >> 7) & 1;
    const int x2 = ((e >> 9) ^ (e >> 6)) & 1;
    return e ^ (x4 << 4) ^ (x3 << 3) ^ (x2 << 2);
}

// Persistent cooperative kernel (R11 structure verbatim; u fused in prologue).
// 256 threads/row; stage buffer (16 KB, linear glds dest) + transpose buffer
// (16 KB, swzW). Phases per row: A: *s2, bits 8-11 (stage->trb); B: bits 4-7;
// C: bits 0-3, *u, bits 0-3 (b128); D: bits 4-7; E: bits 8-11, *s1, store.
// Per-wave vmem queue at bottom (oldest->newest): 4 glds, 16 stores;
// s_waitcnt vmcnt(16) retires exactly the glds, keeps stores in flight.
__global__ __launch_bounds__(256, 4) void whvi_kernel(const float* __restrict__ x,
                                                      const float* __restrict__ s1,
                                                      const float* __restrict__ s2,
                                                      const float* __restrict__ g_mu,
                                                      const float* __restrict__ g_rho,
                                                      const float* __restrict__ eps,
                                                      float* __restrict__ out,
                                                      int nrows) {
    __shared__ float stg[D_DIM];  // x stage: linear (glds destination)
    __shared__ float trb[D_DIM];  // transpose buffer: swzW layout
    const int tid = threadIdx.x;
    const int wv = tid >> 6;
    const int l6 = tid & 63;

    // ---- prologue: glds row0 into stage FIRST (oldest vmem ops) ----
    int row = blockIdx.x;
    if (row < nrows) {
        const float* xr = x + (size_t)row * D_DIM;
#pragma unroll
        for (int k = 0; k < 4; ++k)
            gload_lds16(xr + (k << 10) + (wv << 8) + (l6 << 2),
                        &stg[(k << 10) + (wv << 8)]);
    }

    // ---- persistent scale registers (~110 live < 128 VGPR cap, as R11) ----
    float S2r[16], S1r[16];
#pragma unroll
    for (int m = 0; m < 16; ++m) {
        S2r[m] = s2[tid + (m << 8)];
        S1r[m] = s1[tid + (m << 8)];
    }
    // fused u: u[i] = (g_mu[i] + softplus(g_rho[i])*eps[i]) / 64, at the
    // contiguous per-thread indices phase C consumes (i = tid*16 + j).
    float4 U4[4];
#pragma unroll
    for (int c = 0; c < 4; ++c) {
        float uv[4];
#pragma unroll
        for (int j = 0; j < 4; ++j) {
            const int i = (tid << 4) + (c << 2) + j;
            const float r = g_rho[i];
            const float sp = (r > 20.0f) ? r : log1pf(expf(r));
            uv[j] = (g_mu[i] + sp * eps[i]) * 0.015625f;  // 1/64 norm folded
        }
        U4[c] = make_float4(uv[0], uv[1], uv[2], uv[3]);
    }

    asm volatile("s_waitcnt vmcnt(0)" ::: "memory");
    __builtin_amdgcn_s_barrier();
    __builtin_amdgcn_sched_barrier(0);

    for (; row < nrows; row += NWG) {
        const int next = row + NWG;
        v2f w[8];

        // ---- Phase A: read stage (linear), *s2, FWHT bits 8-11, write trb ----
#pragma unroll
        for (int m = 0; m < 16; ++m) {
            const float val = stg[tid + (m << 8)] * S2r[m];
            if (m & 1) w[m >> 1].y = val; else w[m >> 1].x = val;
        }
        radix16(w);
#pragma unroll
        for (int m = 0; m < 16; ++m)
            trb[swzW(tid + (m << 8))] = (m & 1) ? w[m >> 1].y : w[m >> 1].x;
        phase_barrier();  // also: all waves done READING stg

        // ---- prefetch next row into stage (stays in flight all row) ----
        if (next < nrows) {
            const float* xn = x + (size_t)next * D_DIM;
#pragma unroll
            for (int k = 0; k < 4; ++k)
                gload_lds16(xn + (k << 10) + (wv << 8) + (l6 << 2),
                            &stg[(k << 10) + (wv << 8)]);
        }
        __builtin_amdgcn_sched_barrier(0);

        // ---- Phase B: FWHT bits 4-7, in place ----
        {
            const int base = ((tid >> 4) << 8) | (tid & 15);
#pragma unroll
            for (int m = 0; m < 16; ++m) {
                const float val = trb[swzW(base | (m << 4))];
                if (m & 1) w[m >> 1].y = val; else w[m >> 1].x = val;
            }
            radix16(w);
#pragma unroll
            for (int m = 0; m < 16; ++m)
                trb[swzW(base | (m << 4))] = (m & 1) ? w[m >> 1].y : w[m >> 1].x;
        }
        phase_barrier();

        // ---- Phase C: FWHT bits 0-3, *u, FWHT bits 0-3 (b128, in place) ----
        {
            const int cb = tid << 4;
#pragma unroll
            for (int c = 0; c < 4; ++c) {
                const float4 f = *reinterpret_cast<const float4*>(&trb[swzW(cb | (c << 2))]);
                w[2 * c]     = (v2f){f.x, f.y};
                w[2 * c + 1] = (v2f){f.z, f.w};
            }
            radix16(w);
#pragma unroll
            for (int c = 0; c < 4; ++c) {
                w[2 * c]     = pkmul(w[2 * c],     (v2f){U4[c].x, U4[c].y});
                w[2 * c + 1] = pkmul(w[2 * c + 1], (v2f){U4[c].z, U4[c].w});
            }
            radix16(w);
#pragma unroll
            for (int c = 0; c < 4; ++c) {
                const float4 f = make_float4(w[2 * c].x, w[2 * c].y,
                                             w[2 * c + 1].x, w[2 * c + 1].y);
                *reinterpret_cast<float4*>(&trb[swzW(cb | (c << 2))]) = f;
            }
        }
        phase_barrier();

        // ---- Phase D: FWHT bits 4-7, in place ----
        {
            const int base = ((tid >> 4) << 8) | (tid & 15);
#pragma unroll
            for (int m = 0; m < 16; ++m) {
                const float val = trb[swzW(base | (m << 4))];
                if (m & 1) w[m >> 1].y = val; else w[m >> 1].x = val;
            }
            radix16(w);
#pragma unroll
            for (int m = 0; m < 16; ++m)
                trb[swzW(base | (m << 4))] = (m & 1) ? w[m >> 1].y : w[m >> 1].x;
        }
        phase_barrier();

        // ---- Phase E: FWHT bits 8-11, *s1, coalesced b32 stores ----
#pragma unroll
        for (int m = 0; m < 16; ++m) {
            const float val = trb[swzW(tid + (m << 8))];
            if (m & 1) w[m >> 1].y = val; else w[m >> 1].x = val;
        }
        radix16(w);
        float* orow = out + (size_t)row * D_DIM;
#pragma unroll
        for (int m = 0; m < 16; ++m) {
            const float val = (m & 1) ? w[m >> 1].y : w[m >> 1].x;
            orow[tid + (m << 8)] = val * S1r[m];
        }

        // ---- bottom: retire exactly the glds (keep stores in flight),
        //      then barrier (trb reuse by next A + stage readiness) ----
        asm volatile("s_waitcnt vmcnt(16)" ::: "memory");
        asm volatile("s_waitcnt lgkmcnt(0)" ::: "memory");
        __builtin_amdgcn_s_barrier();
        __builtin_amdgcn_sched_barrier(0);
    }
}

extern "C" void kernel_launch(void* const* d_in, const int* in_sizes, int n_in,
                              void* d_out, int out_size, void* d_ws, size_t ws_size,
                              hipStream_t stream) {
    const float* x     = (const float*)d_in[0];
    const float* s1    = (const float*)d_in[1];
    const float* s2    = (const float*)d_in[2];
    const float* g_mu  = (const float*)d_in[3];
    const float* g_rho = (const float*)d_in[4];
    const float* eps   = (const float*)d_in[5];
    // d_in[6] = H : realized implicitly by the FWHT butterflies.
    float* out = (float*)d_out;

    const int N = in_sizes[0] / D_DIM;

    whvi_kernel<<<NWG, 256, 0, stream>>>(x, s1, s2, g_mu, g_rho, eps, out, N);
}

// Round 18
// 127.032 us; speedup vs baseline: 1.0107x; 1.0107x over previous
//
#include <hip/hip_runtime.h>
#include <math.h>

#define D_DIM 4096
#define NWG 1024  // 4 WGs/CU x 256 CUs, persistent grid-stride (16 rows/WG)

typedef float v2f __attribute__((ext_vector_type(2)));

// ---- packed-f32 butterfly primitives (VOP3P) ----
__device__ __forceinline__ v2f bfly0(v2f a) {
    v2f d;
    asm("v_pk_add_f32 %0, %1, %2 op_sel:[0,1] op_sel_hi:[0,1] neg_hi:[0,1]"
        : "=v"(d) : "v"(a), "v"(a));
    return d;
}
__device__ __forceinline__ v2f pkadd(v2f a, v2f b) {
    v2f d; asm("v_pk_add_f32 %0, %1, %2" : "=v"(d) : "v"(a), "v"(b)); return d;
}
__device__ __forceinline__ v2f pksub(v2f a, v2f b) {
    v2f d; asm("v_pk_add_f32 %0, %1, %2 neg_lo:[0,1] neg_hi:[0,1]" : "=v"(d) : "v"(a), "v"(b)); return d;
}
__device__ __forceinline__ v2f pkmul(v2f a, v2f b) {
    v2f d; asm("v_pk_mul_f32 %0, %1, %2" : "=v"(d) : "v"(a), "v"(b)); return d;
}

// In-register FWHT over 4 bits: 16 values as 8 packed v2f.
__device__ __forceinline__ void radix16(v2f w[8]) {
#pragma unroll
    for (int p = 0; p < 8; ++p) w[p] = bfly0(w[p]);
#pragma unroll
    for (int s = 0; s < 3; ++s) {
        const int d = 1 << s;
#pragma unroll
        for (int p = 0; p < 8; ++p) {
            if (!(p & d)) {
                const v2f a = w[p];
                const v2f b = w[p + d];
                w[p]     = pkadd(a, b);
                w[p + d] = pksub(a, b);
            }
        }
    }
}

// async global->LDS, 16 B per lane; LDS dest = wave-uniform base + lane*16.
__device__ __forceinline__ void gload_lds16(const float* g, float* lp) {
    __builtin_amdgcn_global_load_lds(
        (const __attribute__((address_space(1))) void*)g,
        (__attribute__((address_space(3))) void*)lp, 16, 0, 0);
}

// Phase barrier: drain DS ops only (NOT vmcnt -> glds prefetch stays in
// flight across barriers; __syncthreads would emit vmcnt(0) and kill it).
__device__ __forceinline__ void phase_barrier() {
    asm volatile("s_waitcnt lgkmcnt(0)" ::: "memory");
    __builtin_amdgcn_s_barrier();
    __builtin_amdgcn_sched_barrier(0);
}

// PIN a value into a VGPR: as an asm output it can NOT be rematerialized, so
// the "memory" clobbers in phase_barrier cannot force per-row reloads or
// softplus recompute (the R17 regression: VGPR_Count=56, VALUBusy 26.5%).
__device__ __forceinline__ void pin(float& v) { asm volatile("" : "+v"(v)); }

// Rank-complete transpose-buffer swizzle (verified R11):
//   b4 ^= e8 ^ e5 ;  b3 ^= e7 ;  b2 ^= e9 ^ e6
// Phases A/E (stride-256) and B/D (stride-16): 2-way banks (free);
// phase C b128: at the bank floor. Bijective involution; bits 1:0 untouched.
__device__ __forceinline__ int swzW(int e) {
    const int x4 = ((e >> 8) ^ (e >> 5)) & 1;
    const int x3 = (e >> 7) & 1;
    const int x2 = ((e >> 9) ^ (e >> 6)) & 1;
    return e ^ (x4 << 4) ^ (x3 << 3) ^ (x2 << 2);
}

// Persistent cooperative kernel (R11 structure; u fused in prologue; all 48
// persistent scalars PINNED into VGPRs). 256 threads/row; stage (16 KB,
// linear glds dest) + transpose buffer (16 KB, swzW). Phases per row:
// A: *s2, bits 8-11 (stage->trb); B: bits 4-7; C: bits 0-3, *u, bits 0-3
// (b128); D: bits 4-7; E: bits 8-11, *s1, store. Bottom vmcnt(16) retires
// exactly the 4 glds (16 stores stay in flight).
__global__ __launch_bounds__(256, 4) void whvi_kernel(const float* __restrict__ x,
                                                      const float* __restrict__ s1,
                                                      const float* __restrict__ s2,
                                                      const float* __restrict__ g_mu,
                                                      const float* __restrict__ g_rho,
                                                      const float* __restrict__ eps,
                                                      float* __restrict__ out,
                                                      int nrows) {
    __shared__ float stg[D_DIM];  // x stage: linear (glds destination)
    __shared__ float trb[D_DIM];  // transpose buffer: swzW layout
    const int tid = threadIdx.x;
    const int wv = tid >> 6;
    const int l6 = tid & 63;

    // ---- prologue: glds row0 into stage FIRST (oldest vmem ops) ----
    int row = blockIdx.x;
    if (row < nrows) {
        const float* xr = x + (size_t)row * D_DIM;
#pragma unroll
        for (int k = 0; k < 4; ++k)
            gload_lds16(xr + (k << 10) + (wv << 8) + (l6 << 2),
                        &stg[(k << 10) + (wv << 8)]);
    }

    // ---- persistent scales + fused u, then PIN all 48 into VGPRs ----
    float S2r[16], S1r[16];
#pragma unroll
    for (int m = 0; m < 16; ++m) {
        S2r[m] = s2[tid + (m << 8)];
        S1r[m] = s1[tid + (m << 8)];
    }
    float Ur[16];
#pragma unroll
    for (int j = 0; j < 16; ++j) {
        const int i = (tid << 4) + j;  // contiguous per-thread (phase-C layout)
        const float r = g_rho[i];
        const float sp = (r > 20.0f) ? r : log1pf(expf(r));
        Ur[j] = (g_mu[i] + sp * eps[i]) * 0.015625f;  // 1/64 norm folded
    }
#pragma unroll
    for (int m = 0; m < 16; ++m) { pin(S2r[m]); pin(S1r[m]); pin(Ur[m]); }

    asm volatile("s_waitcnt vmcnt(0)" ::: "memory");
    __builtin_amdgcn_s_barrier();
    __builtin_amdgcn_sched_barrier(0);

    for (; row < nrows; row += NWG) {
        const int next = row + NWG;
        v2f w[8];

        // ---- Phase A: read stage (linear), *s2, FWHT bits 8-11, write trb ----
#pragma unroll
        for (int m = 0; m < 16; ++m) {
            const float val = stg[tid + (m << 8)] * S2r[m];
            if (m & 1) w[m >> 1].y = val; else w[m >> 1].x = val;
        }
        radix16(w);
#pragma unroll
        for (int m = 0; m < 16; ++m)
            trb[swzW(tid + (m << 8))] = (m & 1) ? w[m >> 1].y : w[m >> 1].x;
        phase_barrier();  // also: all waves done READING stg

        // ---- prefetch next row into stage (stays in flight all row) ----
        if (next < nrows) {
            const float* xn = x + (size_t)next * D_DIM;
#pragma unroll
            for (int k = 0; k < 4; ++k)
                gload_lds16(xn + (k << 10) + (wv << 8) + (l6 << 2),
                            &stg[(k << 10) + (wv << 8)]);
        }
        __builtin_amdgcn_sched_barrier(0);

        // ---- Phase B: FWHT bits 4-7, in place ----
        {
            const int base = ((tid >> 4) << 8) | (tid & 15);
#pragma unroll
            for (int m = 0; m < 16; ++m) {
                const float val = trb[swzW(base | (m << 4))];
                if (m & 1) w[m >> 1].y = val; else w[m >> 1].x = val;
            }
            radix16(w);
#pragma unroll
            for (int m = 0; m < 16; ++m)
                trb[swzW(base | (m << 4))] = (m & 1) ? w[m >> 1].y : w[m >> 1].x;
        }
        phase_barrier();

        // ---- Phase C: FWHT bits 0-3, *u, FWHT bits 0-3 (b128, in place) ----
        {
            const int cb = tid << 4;
#pragma unroll
            for (int c = 0; c < 4; ++c) {
                const float4 f = *reinterpret_cast<const float4*>(&trb[swzW(cb | (c << 2))]);
                w[2 * c]     = (v2f){f.x, f.y};
                w[2 * c + 1] = (v2f){f.z, f.w};
            }
            radix16(w);
#pragma unroll
            for (int j = 0; j < 8; ++j)
                w[j] = pkmul(w[j], (v2f){Ur[2 * j], Ur[2 * j + 1]});
            radix16(w);
#pragma unroll
            for (int c = 0; c < 4; ++c) {
                const float4 f = make_float4(w[2 * c].x, w[2 * c].y,
                                             w[2 * c + 1].x, w[2 * c + 1].y);
                *reinterpret_cast<float4*>(&trb[swzW(cb | (c << 2))]) = f;
            }
        }
        phase_barrier();

        // ---- Phase D: FWHT bits 4-7, in place ----
        {
            const int base = ((tid >> 4) << 8) | (tid & 15);
#pragma unroll
            for (int m = 0; m < 16; ++m) {
                const float val = trb[swzW(base | (m << 4))];
                if (m & 1) w[m >> 1].y = val; else w[m >> 1].x = val;
            }
            radix16(w);
#pragma unroll
            for (int m = 0; m < 16; ++m)
                trb[swzW(base | (m << 4))] = (m & 1) ? w[m >> 1].y : w[m >> 1].x;
        }
        phase_barrier();

        // ---- Phase E: FWHT bits 8-11, *s1, coalesced b32 stores ----
#pragma unroll
        for (int m = 0; m < 16; ++m) {
            const float val = trb[swzW(tid + (m << 8))];
            if (m & 1) w[m >> 1].y = val; else w[m >> 1].x = val;
        }
        radix16(w);
        float* orow = out + (size_t)row * D_DIM;
#pragma unroll
        for (int m = 0; m < 16; ++m) {
            const float val = (m & 1) ? w[m >> 1].y : w[m >> 1].x;
            orow[tid + (m << 8)] = val * S1r[m];
        }

        // ---- bottom: retire exactly the glds (keep stores in flight),
        //      then barrier (trb reuse by next A + stage readiness) ----
        asm volatile("s_waitcnt vmcnt(16)" ::: "memory");
        asm volatile("s_waitcnt lgkmcnt(0)" ::: "memory");
        __builtin_amdgcn_s_barrier();
        __builtin_amdgcn_sched_barrier(0);
    }
}

extern "C" void kernel_launch(void* const* d_in, const int* in_sizes, int n_in,
                              void* d_out, int out_size, void* d_ws, size_t ws_size,
                              hipStream_t stream) {
    const float* x     = (const float*)d_in[0];
    const float* s1    = (const float*)d_in[1];
    const float* s2    = (const float*)d_in[2];
    const float* g_mu  = (const float*)d_in[3];
    const float* g_rho = (const float*)d_in[4];
    const float* eps   = (const float*)d_in[5];
    // d_in[6] = H : realized implicitly by the FWHT butterflies.
    float* out = (float*)d_out;

    const int N = in_sizes[0] / D_DIM;

    whvi_kernel<<<NWG, 256, 0, stream>>>(x, s1, s2, g_mu, g_rho, eps, out, N);
}

// Round 19
// 112.190 us; speedup vs baseline: 1.1444x; 1.1323x over previous
//
#include <hip/hip_runtime.h>
#include <math.h>

#define D_DIM 4096
#define NWG 1024  // 4 WGs/CU x 256 CUs, persistent grid-stride (16 rows/WG)

typedef float v2f __attribute__((ext_vector_type(2)));

// ---- packed-f32 butterfly primitives (VOP3P) ----
__device__ __forceinline__ v2f bfly0(v2f a) {
    v2f d;
    asm("v_pk_add_f32 %0, %1, %2 op_sel:[0,1] op_sel_hi:[0,1] neg_hi:[0,1]"
        : "=v"(d) : "v"(a), "v"(a));
    return d;
}
__device__ __forceinline__ v2f pkadd(v2f a, v2f b) {
    v2f d; asm("v_pk_add_f32 %0, %1, %2" : "=v"(d) : "v"(a), "v"(b)); return d;
}
__device__ __forceinline__ v2f pksub(v2f a, v2f b) {
    v2f d; asm("v_pk_add_f32 %0, %1, %2 neg_lo:[0,1] neg_hi:[0,1]" : "=v"(d) : "v"(a), "v"(b)); return d;
}
__device__ __forceinline__ v2f pkmul(v2f a, v2f b) {
    v2f d; asm("v_pk_mul_f32 %0, %1, %2" : "=v"(d) : "v"(a), "v"(b)); return d;
}

// In-register FWHT over 4 bits: 16 values as 8 packed v2f.
__device__ __forceinline__ void radix16(v2f w[8]) {
#pragma unroll
    for (int p = 0; p < 8; ++p) w[p] = bfly0(w[p]);
#pragma unroll
    for (int s = 0; s < 3; ++s) {
        const int d = 1 << s;
#pragma unroll
        for (int p = 0; p < 8; ++p) {
            if (!(p & d)) {
                const v2f a = w[p];
                const v2f b = w[p + d];
                w[p]     = pkadd(a, b);
                w[p + d] = pksub(a, b);
            }
        }
    }
}

// async global->LDS, 16 B per lane; LDS dest = wave-uniform base + lane*16.
__device__ __forceinline__ void gload_lds16(const float* g, float* lp) {
    __builtin_amdgcn_global_load_lds(
        (const __attribute__((address_space(1))) void*)g,
        (__attribute__((address_space(3))) void*)lp, 16, 0, 0);
}

// Phase barrier: drain DS ops only (NOT vmcnt -> glds prefetch stays in
// flight across barriers; __syncthreads would emit vmcnt(0) and kill it).
__device__ __forceinline__ void phase_barrier() {
    asm volatile("s_waitcnt lgkmcnt(0)" ::: "memory");
    __builtin_amdgcn_s_barrier();
    __builtin_amdgcn_sched_barrier(0);
}

// Rank-complete transpose-buffer swizzle (re-derived per access pattern):
//   b4 ^= e8 ^ e5 ;  b3 ^= e7 ;  b2 ^= e9 ^ e6
// - Phase A/E (e = m<<8 | tid):      2-way banks (free)
// - Phase B/D (e = t74<<8|m<<4|t30): 2-way banks (free)
// - Phase C   (e = tid<<4|c<<2|j):   exactly the b128 bank floor
// Triangular XOR (high bits into low) -> bijective involution; bits 1:0
// untouched -> b128 contiguity + 16B alignment preserved.
__device__ __forceinline__ int swzW(int e) {
    const int x4 = ((e >> 8) ^ (e >> 5)) & 1;
    const int x3 = (e >> 7) & 1;
    const int x2 = ((e >> 9) ^ (e >> 6)) & 1;
    return e ^ (x4 << 4) ^ (x3 << 3) ^ (x2 << 2);
}

// u in NATURAL order, 1/64 FWHT normalization folded in.
__global__ void compute_u_kernel(const float* __restrict__ g_mu,
                                 const float* __restrict__ g_rho,
                                 const float* __restrict__ eps,
                                 float* __restrict__ u) {
    const int i = blockIdx.x * blockDim.x + threadIdx.x;
    if (i < D_DIM) {
        const float r = g_rho[i];
        const float sp = (r > 20.0f) ? r : log1pf(expf(r));
        u[i] = (g_mu[i] + sp * eps[i]) * 0.015625f;
    }
}

// Persistent cooperative kernel (round-10 structure, spill-free + clean banks).
// 256 threads/row; stage buffer (16 KB, linear glds dest) + transpose buffer
// (16 KB, swzW). Phases per row: A: *s2, bits 8-11 (stage->trb); B: bits 4-7;
// C: bits 0-3, *u, bits 0-3 (b128); D: bits 4-7; E: bits 8-11, *s1, store.
// Per-wave vmem queue at bottom (oldest->newest): 4 glds, 16 stores;
// s_waitcnt vmcnt(16) retires exactly the glds, keeps stores in flight.
__global__ __launch_bounds__(256, 4) void whvi_kernel(const float* __restrict__ x,
                                                      const float* __restrict__ s1,
                                                      const float* __restrict__ s2,
                                                      const float* __restrict__ u,
                                                      float* __restrict__ out,
                                                      int nrows) {
    __shared__ float stg[D_DIM];  // x stage: linear (glds destination)
    __shared__ float trb[D_DIM];  // transpose buffer: swzW layout
    const int tid = threadIdx.x;
    const int wv = tid >> 6;
    const int l6 = tid & 63;

    // ---- persistent scale registers (fits: ~110 live < 128 VGPR cap) ----
    float S2r[16], S1r[16];
#pragma unroll
    for (int m = 0; m < 16; ++m) {
        S2r[m] = s2[tid + (m << 8)];
        S1r[m] = s1[tid + (m << 8)];
    }
    float4 U4[4];
#pragma unroll
    for (int c = 0; c < 4; ++c)
        U4[c] = *reinterpret_cast<const float4*>(u + (tid << 4) + (c << 2));

    // ---- prologue: glds row0 into stage, drain, barrier ----
    int row = blockIdx.x;
    if (row < nrows) {
        const float* xr = x + (size_t)row * D_DIM;
#pragma unroll
        for (int k = 0; k < 4; ++k)
            gload_lds16(xr + (k << 10) + (wv << 8) + (l6 << 2),
                        &stg[(k << 10) + (wv << 8)]);
    }
    asm volatile("s_waitcnt vmcnt(0)" ::: "memory");
    __builtin_amdgcn_s_barrier();
    __builtin_amdgcn_sched_barrier(0);

    for (; row < nrows; row += NWG) {
        const int next = row + NWG;
        v2f w[8];

        // ---- Phase A: read stage (linear), *s2, FWHT bits 8-11, write trb ----
#pragma unroll
        for (int m = 0; m < 16; ++m) {
            const float val = stg[tid + (m << 8)] * S2r[m];
            if (m & 1) w[m >> 1].y = val; else w[m >> 1].x = val;
        }
        radix16(w);
#pragma unroll
        for (int m = 0; m < 16; ++m)
            trb[swzW(tid + (m << 8))] = (m & 1) ? w[m >> 1].y : w[m >> 1].x;
        phase_barrier();  // also: all waves done READING stg

        // ---- prefetch next row into stage (stays in flight all row) ----
        if (next < nrows) {
            const float* xn = x + (size_t)next * D_DIM;
#pragma unroll
            for (int k = 0; k < 4; ++k)
                gload_lds16(xn + (k << 10) + (wv << 8) + (l6 << 2),
                            &stg[(k << 10) + (wv << 8)]);
        }
        __builtin_amdgcn_sched_barrier(0);

        // ---- Phase B: FWHT bits 4-7, in place ----
        {
            const int base = ((tid >> 4) << 8) | (tid & 15);
#pragma unroll
            for (int m = 0; m < 16; ++m) {
                const float val = trb[swzW(base | (m << 4))];
                if (m & 1) w[m >> 1].y = val; else w[m >> 1].x = val;
            }
            radix16(w);
#pragma unroll
            for (int m = 0; m < 16; ++m)
                trb[swzW(base | (m << 4))] = (m & 1) ? w[m >> 1].y : w[m >> 1].x;
        }
        phase_barrier();

        // ---- Phase C: FWHT bits 0-3, *u, FWHT bits 0-3 (b128, in place) ----
        {
            const int cb = tid << 4;
#pragma unroll
            for (int c = 0; c < 4; ++c) {
                const float4 f = *reinterpret_cast<const float4*>(&trb[swzW(cb | (c << 2))]);
                w[2 * c]     = (v2f){f.x, f.y};
                w[2 * c + 1] = (v2f){f.z, f.w};
            }
            radix16(w);
#pragma unroll
            for (int c = 0; c < 4; ++c) {
                w[2 * c]     = pkmul(w[2 * c],     (v2f){U4[c].x, U4[c].y});
                w[2 * c + 1] = pkmul(w[2 * c + 1], (v2f){U4[c].z, U4[c].w});
            }
            radix16(w);
#pragma unroll
            for (int c = 0; c < 4; ++c) {
                const float4 f = make_float4(w[2 * c].x, w[2 * c].y,
                                             w[2 * c + 1].x, w[2 * c + 1].y);
                *reinterpret_cast<float4*>(&trb[swzW(cb | (c << 2))]) = f;
            }
        }
        phase_barrier();

        // ---- Phase D: FWHT bits 4-7, in place ----
        {
            const int base = ((tid >> 4) << 8) | (tid & 15);
#pragma unroll
            for (int m = 0; m < 16; ++m) {
                const float val = trb[swzW(base | (m << 4))];
                if (m & 1) w[m >> 1].y = val; else w[m >> 1].x = val;
            }
            radix16(w);
#pragma unroll
            for (int m = 0; m < 16; ++m)
                trb[swzW(base | (m << 4))] = (m & 1) ? w[m >> 1].y : w[m >> 1].x;
        }
        phase_barrier();

        // ---- Phase E: FWHT bits 8-11, *s1, coalesced b32 stores ----
#pragma unroll
        for (int m = 0; m < 16; ++m) {
            const float val = trb[swzW(tid + (m << 8))];
            if (m & 1) w[m >> 1].y = val; else w[m >> 1].x = val;
        }
        radix16(w);
        float* orow = out + (size_t)row * D_DIM;
#pragma unroll
        for (int m = 0; m < 16; ++m) {
            const float val = (m & 1) ? w[m >> 1].y : w[m >> 1].x;
            orow[tid + (m << 8)] = val * S1r[m];
        }

        // ---- bottom: retire exactly the glds (keep stores in flight),
        //      then barrier (trb reuse by next A + stage readiness) ----
        asm volatile("s_waitcnt vmcnt(16)" ::: "memory");
        asm volatile("s_waitcnt lgkmcnt(0)" ::: "memory");
        __builtin_amdgcn_s_barrier();
        __builtin_amdgcn_sched_barrier(0);
    }
}

extern "C" void kernel_launch(void* const* d_in, const int* in_sizes, int n_in,
                              void* d_out, int out_size, void* d_ws, size_t ws_size,
                              hipStream_t stream) {
    const float* x     = (const float*)d_in[0];
    const float* s1    = (const float*)d_in[1];
    const float* s2    = (const float*)d_in[2];
    const float* g_mu  = (const float*)d_in[3];
    const float* g_rho = (const float*)d_in[4];
    const float* eps   = (const float*)d_in[5];
    // d_in[6] = H : realized implicitly by the FWHT butterflies.

    float* u   = (float*)d_ws;
    float* out = (float*)d_out;

    const int N = in_sizes[0] / D_DIM;

    compute_u_kernel<<<(D_DIM + 255) / 256, 256, 0, stream>>>(g_mu, g_rho, eps, u);
    whvi_kernel<<<NWG, 256, 0, stream>>>(x, s1, s2, u, out, N);
}